// Round 14
// baseline (409.041 us; speedup 1.0000x reference)
//
#include <hip/hip_runtime.h>
#include <math.h>

#define N_NODES 10000
#define N_EDGES 640000
#define NB      100                 // hist chunks
#define CH      (N_EDGES / NB)      // 6400 edges per chunk
#define HP      10016               // histogram pitch (padded)
#define GB      313                 // gemm blocks per matrix
#define NBLK    40                  // mid blocks (co-resident)
#define NPB2    250                 // nodes per mid block
#define MID0    (NB + 2 * GB)       // first mid block id in k_front

typedef unsigned short ushort4_t __attribute__((ext_vector_type(4)));
typedef unsigned short ushort8_t __attribute__((ext_vector_type(8)));

__device__ inline unsigned short f2bf(float f) {
    unsigned int u = __float_as_uint(f);
    u = (u + 0x7FFFu + ((u >> 16) & 1u)) >> 16;   // RNE
    return (unsigned short)u;
}
__device__ inline float bf2f(unsigned short s) {
    return __uint_as_float(((unsigned int)s) << 16);
}

// bar layout: [0..7] cnt slots, [8..15] gen slots, [16..115] hist flags, [116] aggdone
__device__ __forceinline__ void gbar(int* bar, int slot, int nblk) {
    __syncthreads();
    if (threadIdx.x == 0) {
        int* cnt = bar + slot;
        int* gen = bar + 8 + slot;
        int g = atomicAdd(gen, 0);
        __threadfence();
        if (atomicAdd(cnt, 1) == nblk - 1) {
            __threadfence();
            atomicAdd(gen, 1);
        } else {
            while (atomicAdd(gen, 0) == g) __builtin_amdgcn_s_sleep(4);
        }
        __threadfence();
    }
    __syncthreads();
}

// ---- kernel 1: hist(+rank) [0,NB) || dual GEMM [NB,MID0) || mid (spin) [MID0,MID0+NBLK) ----
__global__ __launch_bounds__(256) void k_front(const int* __restrict__ dst,
                                               unsigned short* __restrict__ hmat,
                                               unsigned short* __restrict__ rank,
                                               int* bar,
                                               const float* __restrict__ X,
                                               const float* __restrict__ W1,
                                               const float* __restrict__ Wdown,
                                               const float* __restrict__ bdown,
                                               unsigned short* __restrict__ outT,
                                               float* __restrict__ outB,
                                               int* __restrict__ rangesum,
                                               int* __restrict__ offsets,
                                               float* __restrict__ dis,
                                               int* __restrict__ bmat, int n) {
    __shared__ char smem[81920];     // union: hist 40KB | gemm 16+64KB | mid ~1.2KB
    int t = threadIdx.x;
    int bid = blockIdx.x;

    if (bid < NB) {
        // ---------------- histogram + rank ----------------
        int* hs = (int*)smem;
        if (bid == 0 && t < 16) bar[t] = 0;          // gbar slots for mid
        for (int j = t; j < HP; j += 256) hs[j] = 0;
        __syncthreads();
        int base = bid * CH;
#pragma unroll 4
        for (int j = t; j < CH; j += 256) {
            int r = atomicAdd(&hs[dst[base + j]], 1);
            rank[base + j] = (unsigned short)r;
        }
        __syncthreads();
        unsigned short* out = hmat + bid * HP;
        for (int j = t; j < N_NODES; j += 256) out[j] = (unsigned short)hs[j];
        __syncthreads();
        if (t == 0) {
            __threadfence();
            atomicExch(&bar[16 + bid], 1);           // publish chunk done
        }
        return;
    }

    if (bid < MID0) {
        // ---------------- dual GEMM ----------------
        float* xs = (float*)smem;                 // 32*128 f32
        float* wsm = (float*)(smem + 16384);      // 128*128 f32
        int gid = bid - NB;
        int which = (gid >= GB) ? 1 : 0;
        int bx = which ? gid - GB : gid;
        int tile0 = bx * 32;
        const float* W = which ? Wdown : W1;

        const float4* Wv = (const float4*)W;
        float4* wsv = (float4*)wsm;
#pragma unroll
        for (int q = 0; q < 16; ++q) wsv[t + 256 * q] = Wv[t + 256 * q];

        const float4* Xv = (const float4*)X;
        float4* xsv = (float4*)xs;
#pragma unroll
        for (int q = 0; q < 4; ++q) {
            int idx = t + 256 * q;
            int row = tile0 + (idx >> 5);
            float4 v = make_float4(0.f, 0.f, 0.f, 0.f);
            if (row < n) v = Xv[(size_t)row * 32 + (idx & 31)];
            xsv[idx] = v;
        }
        __syncthreads();

        int c4 = t & 31;
        int rg = t >> 5;
        float4 acc[4];
#pragma unroll
        for (int p = 0; p < 4; ++p) acc[p] = make_float4(0.f, 0.f, 0.f, 0.f);

        const float4* wsr = (const float4*)wsm;
        const float4* xsr = (const float4*)xs;
#pragma unroll 4
        for (int kq = 0; kq < 32; ++kq) {
            float4 w0 = wsr[(4 * kq + 0) * 32 + c4];
            float4 w1 = wsr[(4 * kq + 1) * 32 + c4];
            float4 w2 = wsr[(4 * kq + 2) * 32 + c4];
            float4 w3 = wsr[(4 * kq + 3) * 32 + c4];
#pragma unroll
            for (int p = 0; p < 4; ++p) {
                float4 xv = xsr[(rg * 4 + p) * 32 + kq];
                acc[p].x += xv.x * w0.x + xv.y * w1.x + xv.z * w2.x + xv.w * w3.x;
                acc[p].y += xv.x * w0.y + xv.y * w1.y + xv.z * w2.y + xv.w * w3.y;
                acc[p].z += xv.x * w0.z + xv.y * w1.z + xv.z * w2.z + xv.w * w3.z;
                acc[p].w += xv.x * w0.w + xv.y * w1.w + xv.z * w2.w + xv.w * w3.w;
            }
        }
        if (which == 0) {
#pragma unroll
            for (int p = 0; p < 4; ++p) {
                int row = tile0 + rg * 4 + p;
                if (row < n) {
                    ushort4_t o;
                    o[0] = f2bf(acc[p].x); o[1] = f2bf(acc[p].y);
                    o[2] = f2bf(acc[p].z); o[3] = f2bf(acc[p].w);
                    ((ushort4_t*)outT)[(size_t)row * 32 + c4] = o;
                }
            }
        } else {
            float4 bv = ((const float4*)bdown)[c4];
#pragma unroll
            for (int p = 0; p < 4; ++p) {
                int row = tile0 + rg * 4 + p;
                if (row < n) {
                    float4 o;
                    o.x = acc[p].x + bv.x; o.y = acc[p].y + bv.y;
                    o.z = acc[p].z + bv.z; o.w = acc[p].w + bv.w;
                    ((float4*)outB)[(size_t)row * 32 + c4] = o;
                }
            }
        }
        return;
    }

    // ---------------- mid: wait for all hists, then colsum+scan+base ----------------
    int mb = bid - MID0;
    if (t < NB) {
        while (atomicAdd(&bar[16 + t], 0) != 1) __builtin_amdgcn_s_sleep(8);
    }
    __syncthreads();
    __threadfence();

    int* sc  = (int*)smem;             // 256
    int* rsl = (int*)smem + 256;       // NBLK
    int* sPp = (int*)smem + 256 + 64;  // 1
    int i = mb * NPB2 + t;
    bool act = (t < NPB2);

    int s = 0;
    if (act) {
#pragma unroll 10
        for (int bb = 0; bb < NB; ++bb) s += hmat[bb * HP + i];
        dis[i] = rsqrtf((float)(s + 1));   // +1 self-loop
    }
    sc[t] = s;
    __syncthreads();
#pragma unroll
    for (int off = 1; off < 256; off <<= 1) {
        int v = (t >= off) ? sc[t - off] : 0;
        __syncthreads();
        sc[t] += v;
        __syncthreads();
    }
    int lofs = sc[t] - s;
    if (t == 255) rangesum[mb] = sc[255];
    gbar(bar, 0, NBLK);

    if (t < NBLK) rsl[t] = rangesum[t];
    __syncthreads();
    if (t == 0) {
        int P = 0;
        for (int bb = 0; bb < mb; ++bb) P += rsl[bb];
        sPp[0] = P;
        if (mb == NBLK - 1) offsets[N_NODES] = P + rsl[mb];
    }
    __syncthreads();
    if (act) {
        int run = sPp[0] + lofs;
        offsets[i] = run;
#pragma unroll 10
        for (int bb = 0; bb < NB; ++bb) {
            bmat[bb * HP + i] = run;
            run += hmat[bb * HP + i];
        }
    }
}

// ---- kernel 2: edge-parallel scatter (2500 blocks); block 0 resets flags+aggdone ----
__global__ __launch_bounds__(256) void k_scatter_ep(const int* __restrict__ src,
                                                    const int* __restrict__ dst,
                                                    const unsigned short* __restrict__ rank,
                                                    const int* __restrict__ bmat,
                                                    const float* __restrict__ dis,
                                                    int2* __restrict__ rec,
                                                    int* bar) {
    if (blockIdx.x == 0 && threadIdx.x < NB + 1)
        atomicExch(&bar[16 + threadIdx.x], 0);        // flags[0..99] + aggdone
    int e = blockIdx.x * 256 + threadIdx.x;           // grid covers E exactly
    int b = blockIdx.x / (CH / 256);                  // 25 blocks per chunk
    int d = dst[e];
    int s = src[e];
    int r = rank[e];
    int pos = bmat[b * HP + d] + r;
    rec[pos] = make_int2(s, __float_as_int(dis[s]));
}

// ---- block-per-node agg edge loop (16 col-lanes x 16 edge-subsets, packed rec) ----
#define AGG_EDGE_LOOP_B                                                        \
    float acc[8];                                                              \
    _Pragma("unroll") for (int j = 0; j < 8; ++j) acc[j] = 0.f;                \
    int e = e0 + es;                                                           \
    for (; e + 48 < e1; e += 64) {                                             \
        int2 r0 = rec[e], r1 = rec[e + 16], r2 = rec[e + 32], r3 = rec[e + 48];\
        float w0 = __int_as_float(r0.y), w1 = __int_as_float(r1.y);            \
        float w2 = __int_as_float(r2.y), w3 = __int_as_float(r3.y);            \
        ushort8_t v0 = T8[(size_t)r0.x * 16 + c8];                             \
        ushort8_t v1 = T8[(size_t)r1.x * 16 + c8];                             \
        ushort8_t v2 = T8[(size_t)r2.x * 16 + c8];                             \
        ushort8_t v3 = T8[(size_t)r3.x * 16 + c8];                             \
        _Pragma("unroll") for (int j = 0; j < 8; ++j)                          \
            acc[j] += w0 * bf2f(v0[j]) + w1 * bf2f(v1[j]) +                    \
                      w2 * bf2f(v2[j]) + w3 * bf2f(v3[j]);                     \
    }                                                                          \
    for (; e + 16 < e1; e += 32) {                                             \
        int2 r0 = rec[e], r1 = rec[e + 16];                                    \
        float w0 = __int_as_float(r0.y), w1 = __int_as_float(r1.y);            \
        ushort8_t v0 = T8[(size_t)r0.x * 16 + c8];                             \
        ushort8_t v1 = T8[(size_t)r1.x * 16 + c8];                             \
        _Pragma("unroll") for (int j = 0; j < 8; ++j)                          \
            acc[j] += w0 * bf2f(v0[j]) + w1 * bf2f(v1[j]);                     \
    }                                                                          \
    if (e < e1) {                                                              \
        int2 r0 = rec[e];                                                      \
        float w0 = __int_as_float(r0.y);                                       \
        ushort8_t v0 = T8[(size_t)r0.x * 16 + c8];                             \
        _Pragma("unroll") for (int j = 0; j < 8; ++j)                          \
            acc[j] += w0 * bf2f(v0[j]);                                        \
    }                                                                          \
    _Pragma("unroll") for (int j = 0; j < 8; ++j) {                            \
        acc[j] += __shfl_xor(acc[j], 16, 64);                                  \
        acc[j] += __shfl_xor(acc[j], 32, 64);                                  \
    }

// ---- kernel 3: agg1 [0,n) block-per-node || T2-GEMM [n, n+GB) (spin on aggdone) ----
__global__ __launch_bounds__(256) void k_agg1_gemm(const ushort8_t* __restrict__ T8,
                                                   const float* __restrict__ dis,
                                                   const int* __restrict__ offsets,
                                                   const int2* __restrict__ rec,
                                                   const float* __restrict__ bias,
                                                   const float* __restrict__ W2,
                                                   float* __restrict__ h1out,
                                                   unsigned short* __restrict__ outT2,
                                                   int* bar, int n) {
    __shared__ char smem[16384];     // union: agg red 1.7KB | gemm xs 16KB
    int bid = blockIdx.x;
    int t = threadIdx.x;

    if (bid < n) {
        float (*red)[16][9] = (float (*)[16][9])smem;
        int i = bid;
        int c8 = t & 15;
        int es = t >> 4;
        int wave = t >> 6;
        int lane = t & 63;
        int e0 = offsets[i], e1 = offsets[i + 1];

        AGG_EDGE_LOOP_B

        if (wave > 0 && lane < 16) {
#pragma unroll
            for (int j = 0; j < 8; ++j) red[wave - 1][lane][j] = acc[j];
        }
        __syncthreads();
        if (wave == 0 && lane < 16) {
#pragma unroll
            for (int j = 0; j < 8; ++j)
                acc[j] += red[0][lane][j] + red[1][lane][j] + red[2][lane][j];

            float di = dis[i];
            ushort8_t sv = T8[(size_t)i * 16 + c8];
#pragma unroll
            for (int j = 0; j < 8; ++j) acc[j] += di * bf2f(sv[j]);
#pragma unroll
            for (int j = 0; j < 8; ++j)
                acc[j] = fmaxf(di * acc[j] + bias[c8 * 8 + j], 0.f);

            float4* Y4 = (float4*)h1out;
            Y4[(size_t)i * 32 + c8 * 2]     = make_float4(acc[0], acc[1], acc[2], acc[3]);
            Y4[(size_t)i * 32 + c8 * 2 + 1] = make_float4(acc[4], acc[5], acc[6], acc[7]);
        }
        __syncthreads();
        if (t == 0) {
            __threadfence();
            atomicAdd(&bar[116], 1);
        }
        return;
    }

    // ---------------- T2 = h1 @ W2 after all agg1 blocks done ----------------
    if (t == 0) {
        while (atomicAdd(&bar[116], 0) < n) __builtin_amdgcn_s_sleep(8);
    }
    __syncthreads();
    __threadfence();

    float* xs = (float*)smem;                 // 32*128 f32
    int tile0 = (bid - n) * 32;

    const float4* Xv = (const float4*)h1out;
    float4* xsv = (float4*)xs;
#pragma unroll
    for (int q = 0; q < 4; ++q) {
        int idx = t + 256 * q;
        int row = tile0 + (idx >> 5);
        float4 v = make_float4(0.f, 0.f, 0.f, 0.f);
        if (row < n) v = Xv[(size_t)row * 32 + (idx & 31)];
        xsv[idx] = v;
    }
    __syncthreads();

    int c4 = t & 31;
    int rg = t >> 5;
    float4 acc[4];
#pragma unroll
    for (int p = 0; p < 4; ++p) acc[p] = make_float4(0.f, 0.f, 0.f, 0.f);

    const float4* Wv = (const float4*)W2;     // streamed from L2 (64KB, hot)
    const float4* xsr = (const float4*)xs;
#pragma unroll 4
    for (int kq = 0; kq < 32; ++kq) {
        float4 w0 = Wv[(4 * kq + 0) * 32 + c4];
        float4 w1 = Wv[(4 * kq + 1) * 32 + c4];
        float4 w2 = Wv[(4 * kq + 2) * 32 + c4];
        float4 w3 = Wv[(4 * kq + 3) * 32 + c4];
#pragma unroll
        for (int p = 0; p < 4; ++p) {
            float4 xv = xsr[(rg * 4 + p) * 32 + kq];
            acc[p].x += xv.x * w0.x + xv.y * w1.x + xv.z * w2.x + xv.w * w3.x;
            acc[p].y += xv.x * w0.y + xv.y * w1.y + xv.z * w2.y + xv.w * w3.y;
            acc[p].z += xv.x * w0.z + xv.y * w1.z + xv.z * w2.z + xv.w * w3.z;
            acc[p].w += xv.x * w0.w + xv.y * w1.w + xv.z * w2.w + xv.w * w3.w;
        }
    }
#pragma unroll
    for (int p = 0; p < 4; ++p) {
        int row = tile0 + rg * 4 + p;
        if (row < n) {
            ushort4_t o;
            o[0] = f2bf(acc[p].x); o[1] = f2bf(acc[p].y);
            o[2] = f2bf(acc[p].z); o[3] = f2bf(acc[p].w);
            ((ushort4_t*)outT2)[(size_t)row * 32 + c4] = o;
        }
    }
}

// ---- kernel 4: layer-2 aggregation + residual + all three heads, block-per-node ----
__global__ __launch_bounds__(256) void k_agg2h(const ushort8_t* __restrict__ T8,
                                               const float* __restrict__ dis,
                                               const int* __restrict__ offsets,
                                               const int2* __restrict__ rec,
                                               const float* __restrict__ bias,
                                               const float* __restrict__ resid,
                                               const float* __restrict__ Wlin,
                                               const float* __restrict__ blin,
                                               const float* __restrict__ Wd2,
                                               const float* __restrict__ bd2,
                                               const float* __restrict__ Wd3,
                                               const float* __restrict__ bd3,
                                               float* __restrict__ out1,
                                               float* __restrict__ out2,
                                               float* __restrict__ out3) {
    __shared__ float red[3][16][9];
    __shared__ float hrow[128];
    int i = blockIdx.x;
    int t = threadIdx.x;
    int c8 = t & 15;
    int es = t >> 4;
    int wave = t >> 6;
    int lane = t & 63;
    int e0 = offsets[i], e1 = offsets[i + 1];

    AGG_EDGE_LOOP_B

    if (wave > 0 && lane < 16) {
#pragma unroll
        for (int j = 0; j < 8; ++j) red[wave - 1][lane][j] = acc[j];
    }
    __syncthreads();
    if (wave == 0 && lane < 16) {
#pragma unroll
        for (int j = 0; j < 8; ++j)
            acc[j] += red[0][lane][j] + red[1][lane][j] + red[2][lane][j];

        float di = dis[i];
        ushort8_t sv = T8[(size_t)i * 16 + c8];
#pragma unroll
        for (int j = 0; j < 8; ++j) acc[j] += di * bf2f(sv[j]);

        const float4* rv4 = (const float4*)resid;
        float4 r0 = rv4[(size_t)i * 32 + c8 * 2];
        float4 r1 = rv4[(size_t)i * 32 + c8 * 2 + 1];
#pragma unroll
        for (int j = 0; j < 8; ++j) acc[j] = di * acc[j] + bias[c8 * 8 + j];
        acc[0] += r0.x; acc[1] += r0.y; acc[2] += r0.z; acc[3] += r0.w;
        acc[4] += r1.x; acc[5] += r1.y; acc[6] += r1.z; acc[7] += r1.w;

#pragma unroll
        for (int j = 0; j < 8; ++j) hrow[c8 * 8 + j] = acc[j];
    }
    __syncthreads();

    if (wave == 0) {
        float h0 = hrow[lane];
        float h1 = hrow[64 + lane];
        float p2 = h0 * Wd2[lane] + h1 * Wd2[64 + lane];
        float p3 = h0 * Wd3[lane] + h1 * Wd3[64 + lane];
#pragma unroll
        for (int d = 1; d < 64; d <<= 1) {
            p2 += __shfl_xor(p2, d, 64);
            p3 += __shfl_xor(p3, d, 64);
        }
        if (lane == 0) {
            out2[i] = p2 + bd2[0];
            out3[i] = p3 + bd3[0];
        }
        int c = lane & 15, kg = lane >> 4;
        float z = 0.f;
#pragma unroll 8
        for (int j = 0; j < 32; ++j) {
            int k = kg * 32 + j;
            z += hrow[k] * Wlin[k * 16 + c];
        }
        z += __shfl_xor(z, 16, 64);
        z += __shfl_xor(z, 32, 64);
        z += blin[c];
        float m = z;
#pragma unroll
        for (int d = 1; d < 16; d <<= 1) m = fmaxf(m, __shfl_xor(m, d, 64));
        float ex = expf(z - m);
        float ssum = ex;
#pragma unroll
        for (int d = 1; d < 16; d <<= 1) ssum += __shfl_xor(ssum, d, 64);
        float lsm = z - m - logf(ssum);
        if (lane < 16) out1[(size_t)i * 16 + c] = lsm;
    }
}

extern "C" void kernel_launch(void* const* d_in, const int* in_sizes, int n_in,
                              void* d_out, int out_size, void* d_ws, size_t ws_size,
                              hipStream_t stream) {
    const float* x     = (const float*)d_in[0];
    const int*   ei    = (const int*)d_in[1];
    const float* W1    = (const float*)d_in[2];
    const float* b1    = (const float*)d_in[3];
    const float* W2    = (const float*)d_in[4];
    const float* b2    = (const float*)d_in[5];
    const float* Wlin1 = (const float*)d_in[6];
    const float* blin1 = (const float*)d_in[7];
    const float* Wdeg2 = (const float*)d_in[8];
    const float* bdeg2 = (const float*)d_in[9];
    const float* Wdeg3 = (const float*)d_in[10];
    const float* bdeg3 = (const float*)d_in[11];
    const float* Wdown = (const float*)d_in[12];
    const float* bdown = (const float*)d_in[13];

    const int n = N_NODES, E = N_EDGES;
    const int* src = ei;
    const int* dst = ei + E;

    char* ws = (char*)d_ws;
    int*            bar      = (int*)ws;                          // 128 ints
    unsigned short* hmat     = (unsigned short*)(bar + 128);      // NB*HP u16
    int*            bmat     = (int*)(hmat + NB * HP);            // NB*HP i32
    int*            rangesum = bmat + NB * HP;                    // 64
    int*            offsets  = rangesum + 64;                     // 10048
    float*          dis      = (float*)(offsets + 10048);         // 10016
    unsigned short* rank     = (unsigned short*)(dis + HP);       // E u16
    int2*           rec      = (int2*)(rank + E);                 // E x 8B
    unsigned short* bufT     = (unsigned short*)(rec + E);        // bf16 n*128 (T1/T2)
    float*          bufB     = (float*)(bufT + (size_t)n * 128);  // f32 n*128 (orig)
    float*          bufC     = bufB + (size_t)n * 128;            // f32 n*128 (h1)

    // 1: hist+rank || T1=x@W1, orig=x@Wdown || mid (colsum/scan/base, spin-gated)
    k_front<<<MID0 + NBLK, 256, 0, stream>>>(dst, hmat, rank, bar, x, W1, Wdown,
                                             bdown, bufT, bufB, rangesum,
                                             offsets, dis, bmat, n);
    // 2: edge-parallel scatter (2500 blocks) + flag/counter reset
    k_scatter_ep<<<E / 256, 256, 0, stream>>>(src, dst, rank, bmat, dis, rec, bar);
    // 3: h1 = relu(agg(T1)+b1) (10000 blocks) || T2 = h1@W2 (313 spin-gated blocks)
    k_agg1_gemm<<<n + GB, 256, 0, stream>>>((const ushort8_t*)bufT, dis, offsets,
                                            rec, b1, W2, bufC, bufT, bar, n);
    // 4: h2 = agg(T2) + b2 + orig, fused heads
    float* out1 = (float*)d_out;
    float* out2 = out1 + (size_t)n * 16;
    float* out3 = out2 + n;
    k_agg2h<<<n, 256, 0, stream>>>((const ushort8_t*)bufT, dis, offsets, rec,
                                   b2, bufB, Wlin1, blin1, Wdeg2, bdeg2,
                                   Wdeg3, bdeg3, out1, out2, out3);
}

// Round 15
// 106.969 us; speedup vs baseline: 3.8239x; 3.8239x over previous
//
#include <hip/hip_runtime.h>
#include <math.h>

#define N_NODES 10000
#define N_EDGES 640000
#define NB      100                 // hist chunks
#define CH      (N_EDGES / NB)      // 6400 edges per chunk
#define HP      10016               // histogram pitch (padded)
#define GB      313                 // gemm blocks per matrix
#define NBLK    40                  // mid blocks
#define NPB2    250                 // nodes per mid block
#define MID0    (NB + 2 * GB)       // first mid block id in k_front

typedef unsigned short ushort4_t __attribute__((ext_vector_type(4)));
typedef unsigned short ushort8_t __attribute__((ext_vector_type(8)));

__device__ inline unsigned short f2bf(float f) {
    unsigned int u = __float_as_uint(f);
    u = (u + 0x7FFFu + ((u >> 16) & 1u)) >> 16;   // RNE
    return (unsigned short)u;
}
__device__ inline float bf2f(unsigned short s) {
    return __uint_as_float(((unsigned int)s) << 16);
}

// bar layout: [0..7] cnt slots, [8..15] gen slots, [16..115] hist-done flags
__device__ __forceinline__ void gbar(int* bar, int slot, int nblk) {
    __syncthreads();
    if (threadIdx.x == 0) {
        int* cnt = bar + slot;
        int* gen = bar + 8 + slot;
        int g = atomicAdd(gen, 0);
        __threadfence();
        if (atomicAdd(cnt, 1) == nblk - 1) {
            __threadfence();
            atomicAdd(gen, 1);
        } else {
            while (atomicAdd(gen, 0) == g) __builtin_amdgcn_s_sleep(4);
        }
        __threadfence();
    }
    __syncthreads();
}

// ---- kernel 1: hist(+rank) [0,NB) || dual GEMM [NB,MID0) || mid [MID0,MID0+NBLK) ----
// mid blocks spin on hist-done flags set by blocks 0..99 (always dispatched first -> safe).
__global__ __launch_bounds__(256) void k_front(const int* __restrict__ dst,
                                               unsigned short* __restrict__ hmat,
                                               unsigned short* __restrict__ rank,
                                               int* bar,
                                               const float* __restrict__ X,
                                               const float* __restrict__ W1,
                                               const float* __restrict__ Wdown,
                                               const float* __restrict__ bdown,
                                               unsigned short* __restrict__ outT,
                                               float* __restrict__ outB,
                                               int* __restrict__ rangesum,
                                               int* __restrict__ offsets,
                                               float* __restrict__ dis,
                                               int* __restrict__ bmat, int n) {
    __shared__ char smem[81920];     // union: hist 40KB | gemm 16+64KB | mid ~1.3KB
    int t = threadIdx.x;
    int bid = blockIdx.x;

    if (bid < NB) {
        // ---------------- histogram + rank ----------------
        int* hs = (int*)smem;
        if (bid == 0 && t < 16) bar[t] = 0;          // gbar slots for mid
        for (int j = t; j < HP; j += 256) hs[j] = 0;
        __syncthreads();
        int base = bid * CH;
#pragma unroll 4
        for (int j = t; j < CH; j += 256) {
            int r = atomicAdd(&hs[dst[base + j]], 1);
            rank[base + j] = (unsigned short)r;
        }
        __syncthreads();
        unsigned short* out = hmat + bid * HP;
        for (int j = t; j < N_NODES; j += 256) out[j] = (unsigned short)hs[j];
        __syncthreads();
        if (t == 0) {
            __threadfence();
            atomicExch(&bar[16 + bid], 1);           // publish chunk done
        }
        return;
    }

    if (bid < MID0) {
        // ---------------- dual GEMM ----------------
        float* xs = (float*)smem;                 // 32*128 f32
        float* wsm = (float*)(smem + 16384);      // 128*128 f32
        int gid = bid - NB;
        int which = (gid >= GB) ? 1 : 0;
        int bx = which ? gid - GB : gid;
        int tile0 = bx * 32;
        const float* W = which ? Wdown : W1;

        const float4* Wv = (const float4*)W;
        float4* wsv = (float4*)wsm;
#pragma unroll
        for (int q = 0; q < 16; ++q) wsv[t + 256 * q] = Wv[t + 256 * q];

        const float4* Xv = (const float4*)X;
        float4* xsv = (float4*)xs;
#pragma unroll
        for (int q = 0; q < 4; ++q) {
            int idx = t + 256 * q;
            int row = tile0 + (idx >> 5);
            float4 v = make_float4(0.f, 0.f, 0.f, 0.f);
            if (row < n) v = Xv[(size_t)row * 32 + (idx & 31)];
            xsv[idx] = v;
        }
        __syncthreads();

        int c4 = t & 31;
        int rg = t >> 5;
        float4 acc[4];
#pragma unroll
        for (int p = 0; p < 4; ++p) acc[p] = make_float4(0.f, 0.f, 0.f, 0.f);

        const float4* wsr = (const float4*)wsm;
        const float4* xsr = (const float4*)xs;
#pragma unroll 4
        for (int kq = 0; kq < 32; ++kq) {
            float4 w0 = wsr[(4 * kq + 0) * 32 + c4];
            float4 w1 = wsr[(4 * kq + 1) * 32 + c4];
            float4 w2 = wsr[(4 * kq + 2) * 32 + c4];
            float4 w3 = wsr[(4 * kq + 3) * 32 + c4];
#pragma unroll
            for (int p = 0; p < 4; ++p) {
                float4 xv = xsr[(rg * 4 + p) * 32 + kq];
                acc[p].x += xv.x * w0.x + xv.y * w1.x + xv.z * w2.x + xv.w * w3.x;
                acc[p].y += xv.x * w0.y + xv.y * w1.y + xv.z * w2.y + xv.w * w3.y;
                acc[p].z += xv.x * w0.z + xv.y * w1.z + xv.z * w2.z + xv.w * w3.z;
                acc[p].w += xv.x * w0.w + xv.y * w1.w + xv.z * w2.w + xv.w * w3.w;
            }
        }
        if (which == 0) {
#pragma unroll
            for (int p = 0; p < 4; ++p) {
                int row = tile0 + rg * 4 + p;
                if (row < n) {
                    ushort4_t o;
                    o[0] = f2bf(acc[p].x); o[1] = f2bf(acc[p].y);
                    o[2] = f2bf(acc[p].z); o[3] = f2bf(acc[p].w);
                    ((ushort4_t*)outT)[(size_t)row * 32 + c4] = o;
                }
            }
        } else {
            float4 bv = ((const float4*)bdown)[c4];
#pragma unroll
            for (int p = 0; p < 4; ++p) {
                int row = tile0 + rg * 4 + p;
                if (row < n) {
                    float4 o;
                    o.x = acc[p].x + bv.x; o.y = acc[p].y + bv.y;
                    o.z = acc[p].z + bv.z; o.w = acc[p].w + bv.w;
                    ((float4*)outB)[(size_t)row * 32 + c4] = o;
                }
            }
        }
        return;
    }

    // ---------------- mid: wait for all hist chunks, then colsum+scan+base ----------------
    int mb = bid - MID0;
    if (t < NB) {
        while (atomicAdd(&bar[16 + t], 0) != 1) __builtin_amdgcn_s_sleep(8);
    }
    __syncthreads();
    __threadfence();

    int* sc  = (int*)smem;             // 256
    int* rsl = (int*)smem + 256;       // NBLK
    int* sPp = (int*)smem + 256 + 64;  // 1
    int i = mb * NPB2 + t;
    bool act = (t < NPB2);

    int s = 0;
    if (act) {
#pragma unroll 10
        for (int bb = 0; bb < NB; ++bb) s += hmat[bb * HP + i];
        dis[i] = rsqrtf((float)(s + 1));   // +1 self-loop
    }
    sc[t] = s;
    __syncthreads();
#pragma unroll
    for (int off = 1; off < 256; off <<= 1) {
        int v = (t >= off) ? sc[t - off] : 0;
        __syncthreads();
        sc[t] += v;
        __syncthreads();
    }
    int lofs = sc[t] - s;
    if (t == 255) rangesum[mb] = sc[255];
    gbar(bar, 0, NBLK);

    if (t < NBLK) rsl[t] = rangesum[t];
    __syncthreads();
    if (t == 0) {
        int P = 0;
        for (int bb = 0; bb < mb; ++bb) P += rsl[bb];
        sPp[0] = P;
        if (mb == NBLK - 1) offsets[N_NODES] = P + rsl[mb];
    }
    __syncthreads();
    if (act) {
        int run = sPp[0] + lofs;
        offsets[i] = run;
#pragma unroll 10
        for (int bb = 0; bb < NB; ++bb) {
            bmat[bb * HP + i] = run;
            run += hmat[bb * HP + i];
        }
    }
}

// ---- kernel 2: edge-parallel scatter (2500 blocks); block 0 resets hist flags ----
__global__ __launch_bounds__(256) void k_scatter_ep(const int* __restrict__ src,
                                                    const int* __restrict__ dst,
                                                    const unsigned short* __restrict__ rank,
                                                    const int* __restrict__ bmat,
                                                    const float* __restrict__ dis,
                                                    int2* __restrict__ rec,
                                                    int* bar) {
    if (blockIdx.x == 0 && threadIdx.x < NB)
        atomicExch(&bar[16 + threadIdx.x], 0);        // reset for next call
    int e = blockIdx.x * 256 + threadIdx.x;           // grid covers E exactly
    int b = blockIdx.x / (CH / 256);                  // 25 blocks per chunk
    int d = dst[e];
    int s = src[e];
    int r = rank[e];
    int pos = bmat[b * HP + d] + r;
    rec[pos] = make_int2(s, __float_as_int(dis[s]));  // dis is 40KB, L2-resident
}

// ---- single GEMM (T2 = h1 @ W2, bf16 out) ----
__global__ __launch_bounds__(256) void k_gemm(const float* __restrict__ X,
                                              const float* __restrict__ W,
                                              unsigned short* __restrict__ Y, int n) {
    __shared__ float xs[32 * 128];
    __shared__ float ws[128 * 128];
    int t = threadIdx.x;
    int tile0 = blockIdx.x * 32;

    const float4* Wv = (const float4*)W;
    float4* wsv = (float4*)ws;
#pragma unroll
    for (int q = 0; q < 16; ++q) wsv[t + 256 * q] = Wv[t + 256 * q];

    const float4* Xv = (const float4*)X;
    float4* xsv = (float4*)xs;
#pragma unroll
    for (int q = 0; q < 4; ++q) {
        int idx = t + 256 * q;
        int row = tile0 + (idx >> 5);
        float4 v = make_float4(0.f, 0.f, 0.f, 0.f);
        if (row < n) v = Xv[(size_t)row * 32 + (idx & 31)];
        xsv[idx] = v;
    }
    __syncthreads();

    int c4 = t & 31;
    int rg = t >> 5;
    float4 acc[4];
#pragma unroll
    for (int p = 0; p < 4; ++p) acc[p] = make_float4(0.f, 0.f, 0.f, 0.f);

    const float4* wsr = (const float4*)ws;
    const float4* xsr = (const float4*)xs;
#pragma unroll 4
    for (int kq = 0; kq < 32; ++kq) {
        float4 w0 = wsr[(4 * kq + 0) * 32 + c4];
        float4 w1 = wsr[(4 * kq + 1) * 32 + c4];
        float4 w2 = wsr[(4 * kq + 2) * 32 + c4];
        float4 w3 = wsr[(4 * kq + 3) * 32 + c4];
#pragma unroll
        for (int p = 0; p < 4; ++p) {
            float4 xv = xsr[(rg * 4 + p) * 32 + kq];
            acc[p].x += xv.x * w0.x + xv.y * w1.x + xv.z * w2.x + xv.w * w3.x;
            acc[p].y += xv.x * w0.y + xv.y * w1.y + xv.z * w2.y + xv.w * w3.y;
            acc[p].z += xv.x * w0.z + xv.y * w1.z + xv.z * w2.z + xv.w * w3.z;
            acc[p].w += xv.x * w0.w + xv.y * w1.w + xv.z * w2.w + xv.w * w3.w;
        }
    }
#pragma unroll
    for (int p = 0; p < 4; ++p) {
        int row = tile0 + rg * 4 + p;
        if (row < n) {
            ushort4_t o;
            o[0] = f2bf(acc[p].x); o[1] = f2bf(acc[p].y);
            o[2] = f2bf(acc[p].z); o[3] = f2bf(acc[p].w);
            ((ushort4_t*)Y)[(size_t)row * 32 + c4] = o;
        }
    }
}

// ---- block-per-node agg edge loop (16 col-lanes x 16 edge-subsets, packed rec) ----
#define AGG_EDGE_LOOP_B                                                        \
    float acc[8];                                                              \
    _Pragma("unroll") for (int j = 0; j < 8; ++j) acc[j] = 0.f;                \
    int e = e0 + es;                                                           \
    for (; e + 48 < e1; e += 64) {                                             \
        int2 r0 = rec[e], r1 = rec[e + 16], r2 = rec[e + 32], r3 = rec[e + 48];\
        float w0 = __int_as_float(r0.y), w1 = __int_as_float(r1.y);            \
        float w2 = __int_as_float(r2.y), w3 = __int_as_float(r3.y);            \
        ushort8_t v0 = T8[(size_t)r0.x * 16 + c8];                             \
        ushort8_t v1 = T8[(size_t)r1.x * 16 + c8];                             \
        ushort8_t v2 = T8[(size_t)r2.x * 16 + c8];                             \
        ushort8_t v3 = T8[(size_t)r3.x * 16 + c8];                             \
        _Pragma("unroll") for (int j = 0; j < 8; ++j)                          \
            acc[j] += w0 * bf2f(v0[j]) + w1 * bf2f(v1[j]) +                    \
                      w2 * bf2f(v2[j]) + w3 * bf2f(v3[j]);                     \
    }                                                                          \
    for (; e + 16 < e1; e += 32) {                                             \
        int2 r0 = rec[e], r1 = rec[e + 16];                                    \
        float w0 = __int_as_float(r0.y), w1 = __int_as_float(r1.y);            \
        ushort8_t v0 = T8[(size_t)r0.x * 16 + c8];                             \
        ushort8_t v1 = T8[(size_t)r1.x * 16 + c8];                             \
        _Pragma("unroll") for (int j = 0; j < 8; ++j)                          \
            acc[j] += w0 * bf2f(v0[j]) + w1 * bf2f(v1[j]);                     \
    }                                                                          \
    if (e < e1) {                                                              \
        int2 r0 = rec[e];                                                      \
        float w0 = __int_as_float(r0.y);                                       \
        ushort8_t v0 = T8[(size_t)r0.x * 16 + c8];                             \
        _Pragma("unroll") for (int j = 0; j < 8; ++j)                          \
            acc[j] += w0 * bf2f(v0[j]);                                        \
    }                                                                          \
    _Pragma("unroll") for (int j = 0; j < 8; ++j) {                            \
        acc[j] += __shfl_xor(acc[j], 16, 64);                                  \
        acc[j] += __shfl_xor(acc[j], 32, 64);                                  \
    }

// ---- layer-1 aggregation: h1 = relu(agg(T1)+b1), block-per-node ----
__global__ __launch_bounds__(256) void k_agg1(const ushort8_t* __restrict__ T8,
                                              const float* __restrict__ dis,
                                              const int* __restrict__ offsets,
                                              const int2* __restrict__ rec,
                                              const float* __restrict__ bias,
                                              float* __restrict__ Y) {
    __shared__ float red[3][16][9];
    int i = blockIdx.x;
    int t = threadIdx.x;
    int c8 = t & 15;
    int es = t >> 4;
    int wave = t >> 6;
    int lane = t & 63;
    int e0 = offsets[i], e1 = offsets[i + 1];

    AGG_EDGE_LOOP_B

    if (wave > 0 && lane < 16) {
#pragma unroll
        for (int j = 0; j < 8; ++j) red[wave - 1][lane][j] = acc[j];
    }
    __syncthreads();
    if (wave == 0 && lane < 16) {
#pragma unroll
        for (int j = 0; j < 8; ++j)
            acc[j] += red[0][lane][j] + red[1][lane][j] + red[2][lane][j];

        float di = dis[i];
        ushort8_t sv = T8[(size_t)i * 16 + c8];
#pragma unroll
        for (int j = 0; j < 8; ++j) acc[j] += di * bf2f(sv[j]);
#pragma unroll
        for (int j = 0; j < 8; ++j)
            acc[j] = fmaxf(di * acc[j] + bias[c8 * 8 + j], 0.f);

        float4* Y4 = (float4*)Y;
        Y4[(size_t)i * 32 + c8 * 2]     = make_float4(acc[0], acc[1], acc[2], acc[3]);
        Y4[(size_t)i * 32 + c8 * 2 + 1] = make_float4(acc[4], acc[5], acc[6], acc[7]);
    }
}

// ---- layer-2 aggregation + residual + all three heads, block-per-node ----
__global__ __launch_bounds__(256) void k_agg2h(const ushort8_t* __restrict__ T8,
                                               const float* __restrict__ dis,
                                               const int* __restrict__ offsets,
                                               const int2* __restrict__ rec,
                                               const float* __restrict__ bias,
                                               const float* __restrict__ resid,
                                               const float* __restrict__ Wlin,
                                               const float* __restrict__ blin,
                                               const float* __restrict__ Wd2,
                                               const float* __restrict__ bd2,
                                               const float* __restrict__ Wd3,
                                               const float* __restrict__ bd3,
                                               float* __restrict__ out1,
                                               float* __restrict__ out2,
                                               float* __restrict__ out3) {
    __shared__ float red[3][16][9];
    __shared__ float hrow[128];
    int i = blockIdx.x;
    int t = threadIdx.x;
    int c8 = t & 15;
    int es = t >> 4;
    int wave = t >> 6;
    int lane = t & 63;
    int e0 = offsets[i], e1 = offsets[i + 1];

    AGG_EDGE_LOOP_B

    if (wave > 0 && lane < 16) {
#pragma unroll
        for (int j = 0; j < 8; ++j) red[wave - 1][lane][j] = acc[j];
    }
    __syncthreads();
    if (wave == 0 && lane < 16) {
#pragma unroll
        for (int j = 0; j < 8; ++j)
            acc[j] += red[0][lane][j] + red[1][lane][j] + red[2][lane][j];

        float di = dis[i];
        ushort8_t sv = T8[(size_t)i * 16 + c8];
#pragma unroll
        for (int j = 0; j < 8; ++j) acc[j] += di * bf2f(sv[j]);

        const float4* rv4 = (const float4*)resid;
        float4 r0 = rv4[(size_t)i * 32 + c8 * 2];
        float4 r1 = rv4[(size_t)i * 32 + c8 * 2 + 1];
#pragma unroll
        for (int j = 0; j < 8; ++j) acc[j] = di * acc[j] + bias[c8 * 8 + j];
        acc[0] += r0.x; acc[1] += r0.y; acc[2] += r0.z; acc[3] += r0.w;
        acc[4] += r1.x; acc[5] += r1.y; acc[6] += r1.z; acc[7] += r1.w;

#pragma unroll
        for (int j = 0; j < 8; ++j) hrow[c8 * 8 + j] = acc[j];
    }
    __syncthreads();

    if (wave == 0) {
        float h0 = hrow[lane];
        float h1 = hrow[64 + lane];
        float p2 = h0 * Wd2[lane] + h1 * Wd2[64 + lane];
        float p3 = h0 * Wd3[lane] + h1 * Wd3[64 + lane];
#pragma unroll
        for (int d = 1; d < 64; d <<= 1) {
            p2 += __shfl_xor(p2, d, 64);
            p3 += __shfl_xor(p3, d, 64);
        }
        if (lane == 0) {
            out2[i] = p2 + bd2[0];
            out3[i] = p3 + bd3[0];
        }
        int c = lane & 15, kg = lane >> 4;
        float z = 0.f;
#pragma unroll 8
        for (int j = 0; j < 32; ++j) {
            int k = kg * 32 + j;
            z += hrow[k] * Wlin[k * 16 + c];
        }
        z += __shfl_xor(z, 16, 64);
        z += __shfl_xor(z, 32, 64);
        z += blin[c];
        float m = z;
#pragma unroll
        for (int d = 1; d < 16; d <<= 1) m = fmaxf(m, __shfl_xor(m, d, 64));
        float ex = expf(z - m);
        float ssum = ex;
#pragma unroll
        for (int d = 1; d < 16; d <<= 1) ssum += __shfl_xor(ssum, d, 64);
        float lsm = z - m - logf(ssum);
        if (lane < 16) out1[(size_t)i * 16 + c] = lsm;
    }
}

extern "C" void kernel_launch(void* const* d_in, const int* in_sizes, int n_in,
                              void* d_out, int out_size, void* d_ws, size_t ws_size,
                              hipStream_t stream) {
    const float* x     = (const float*)d_in[0];
    const int*   ei    = (const int*)d_in[1];
    const float* W1    = (const float*)d_in[2];
    const float* b1    = (const float*)d_in[3];
    const float* W2    = (const float*)d_in[4];
    const float* b2    = (const float*)d_in[5];
    const float* Wlin1 = (const float*)d_in[6];
    const float* blin1 = (const float*)d_in[7];
    const float* Wdeg2 = (const float*)d_in[8];
    const float* bdeg2 = (const float*)d_in[9];
    const float* Wdeg3 = (const float*)d_in[10];
    const float* bdeg3 = (const float*)d_in[11];
    const float* Wdown = (const float*)d_in[12];
    const float* bdown = (const float*)d_in[13];

    const int n = N_NODES, E = N_EDGES;
    const int* src = ei;
    const int* dst = ei + E;

    char* ws = (char*)d_ws;
    int*            bar      = (int*)ws;                          // 128 ints
    unsigned short* hmat     = (unsigned short*)(bar + 128);      // NB*HP u16
    int*            bmat     = (int*)(hmat + NB * HP);            // NB*HP i32
    int*            rangesum = bmat + NB * HP;                    // 64
    int*            offsets  = rangesum + 64;                     // 10048
    float*          dis      = (float*)(offsets + 10048);         // 10016
    unsigned short* rank     = (unsigned short*)(dis + HP);       // E u16
    int2*           rec      = (int2*)(rank + E);                 // E x 8B
    unsigned short* bufT     = (unsigned short*)(rec + E);        // bf16 n*128
    float*          bufB     = (float*)(bufT + (size_t)n * 128);  // f32 n*128
    float*          bufC     = bufB + (size_t)n * 128;            // f32 n*128

    // 1: hist+rank || T1=x@W1, orig=x@Wdown || mid (flag-gated, hist-first safe)
    k_front<<<MID0 + NBLK, 256, 0, stream>>>(dst, hmat, rank, bar, x, W1, Wdown,
                                             bdown, bufT, bufB, rangesum,
                                             offsets, dis, bmat, n);
    // 2: edge-parallel scatter (2500 blocks) + flag reset
    k_scatter_ep<<<E / 256, 256, 0, stream>>>(src, dst, rank, bmat, dis, rec, bar);
    // 3: h1 = relu(agg(T1) + b1), block-per-node
    k_agg1<<<n, 256, 0, stream>>>((const ushort8_t*)bufT, dis, offsets, rec,
                                  b1, bufC);
    // 4: T2 = h1 @ W2
    k_gemm<<<(n + 31) / 32, 256, 0, stream>>>(bufC, W2, bufT, n);
    // 5: h2 = agg(T2) + b2 + orig, fused heads
    float* out1 = (float*)d_out;
    float* out2 = out1 + (size_t)n * 16;
    float* out3 = out2 + n;
    k_agg2h<<<n, 256, 0, stream>>>((const ushort8_t*)bufT, dis, offsets, rec,
                                   b2, bufB, Wlin1, blin1, Wdeg2, bdeg2,
                                   Wdeg3, bdeg3, out1, out2, out3);
}

// Round 16
// 104.670 us; speedup vs baseline: 3.9079x; 1.0220x over previous
//
#include <hip/hip_runtime.h>
#include <math.h>

#define N_NODES 10000
#define N_EDGES 640000
#define NB      100                 // hist chunks
#define CH      (N_EDGES / NB)      // 6400 edges per chunk
#define HP      10016               // histogram pitch (padded)
#define GB      313                 // gemm blocks per matrix
#define NBLK    40                  // k_mid blocks (co-resident)
#define NPB2    250                 // nodes per k_mid block

typedef unsigned short ushort4_t __attribute__((ext_vector_type(4)));
typedef unsigned short ushort8_t __attribute__((ext_vector_type(8)));

__device__ inline unsigned short f2bf(float f) {
    unsigned int u = __float_as_uint(f);
    u = (u + 0x7FFFu + ((u >> 16) & 1u)) >> 16;   // RNE
    return (unsigned short)u;
}
__device__ inline float bf2f(unsigned short s) {
    return __uint_as_float(((unsigned int)s) << 16);
}

// ---- device-scope grid barrier ----
__device__ __forceinline__ void gbar(int* bar, int slot, int nblk) {
    __syncthreads();
    if (threadIdx.x == 0) {
        int* cnt = bar + slot;
        int* gen = bar + 8 + slot;
        int g = atomicAdd(gen, 0);
        __threadfence();
        if (atomicAdd(cnt, 1) == nblk - 1) {
            __threadfence();
            atomicAdd(gen, 1);
        } else {
            while (atomicAdd(gen, 0) == g) __builtin_amdgcn_s_sleep(4);
        }
        __threadfence();
    }
    __syncthreads();
}

// ---- fused: blocks [0,NB) = LDS histogram (+edge ranks, u16 out); [NB,..) = dual GEMM ----
__global__ __launch_bounds__(256) void k_hist_gemm2(const int* __restrict__ dst,
                                                    unsigned short* __restrict__ hmat,
                                                    unsigned short* __restrict__ rank,
                                                    int* __restrict__ bar,
                                                    const float* __restrict__ X,
                                                    const float* __restrict__ W1,
                                                    const float* __restrict__ Wdown,
                                                    const float* __restrict__ bdown,
                                                    unsigned short* __restrict__ outT,
                                                    float* __restrict__ outB, int n) {
    __shared__ char smem[81920];     // union: hist 40KB | gemm xs 16KB + ws 64KB
    int t = threadIdx.x;

    if (blockIdx.x < NB) {
        int* hs = (int*)smem;
        if (blockIdx.x == 0 && t < 16) bar[t] = 0;   // zero barrier for k_mid
        for (int j = t; j < HP; j += 256) hs[j] = 0;
        __syncthreads();
        int base = blockIdx.x * CH;
#pragma unroll 4
        for (int j = t; j < CH; j += 256) {
            int r = atomicAdd(&hs[dst[base + j]], 1);
            rank[base + j] = (unsigned short)r;   // rank within (chunk, dst)
        }
        __syncthreads();
        unsigned short* out = hmat + blockIdx.x * HP;
        for (int j = t; j < N_NODES; j += 256) out[j] = (unsigned short)hs[j];
        return;
    }

    // GEMM branch
    float* xs = (float*)smem;                 // 32*128 f32
    float* wsm = (float*)(smem + 16384);      // 128*128 f32
    int bid = blockIdx.x - NB;
    int which = (bid >= GB) ? 1 : 0;
    int bx = which ? bid - GB : bid;
    int tile0 = bx * 32;
    const float* W = which ? Wdown : W1;

    const float4* Wv = (const float4*)W;
    float4* wsv = (float4*)wsm;
#pragma unroll
    for (int q = 0; q < 16; ++q) wsv[t + 256 * q] = Wv[t + 256 * q];

    const float4* Xv = (const float4*)X;
    float4* xsv = (float4*)xs;
#pragma unroll
    for (int q = 0; q < 4; ++q) {
        int idx = t + 256 * q;
        int row = tile0 + (idx >> 5);
        float4 v = make_float4(0.f, 0.f, 0.f, 0.f);
        if (row < n) v = Xv[(size_t)row * 32 + (idx & 31)];
        xsv[idx] = v;
    }
    __syncthreads();

    int c4 = t & 31;
    int rg = t >> 5;
    float4 acc[4];
#pragma unroll
    for (int p = 0; p < 4; ++p) acc[p] = make_float4(0.f, 0.f, 0.f, 0.f);

    const float4* wsr = (const float4*)wsm;
    const float4* xsr = (const float4*)xs;
#pragma unroll 4
    for (int kq = 0; kq < 32; ++kq) {
        float4 w0 = wsr[(4 * kq + 0) * 32 + c4];
        float4 w1 = wsr[(4 * kq + 1) * 32 + c4];
        float4 w2 = wsr[(4 * kq + 2) * 32 + c4];
        float4 w3 = wsr[(4 * kq + 3) * 32 + c4];
#pragma unroll
        for (int p = 0; p < 4; ++p) {
            float4 xv = xsr[(rg * 4 + p) * 32 + kq];
            acc[p].x += xv.x * w0.x + xv.y * w1.x + xv.z * w2.x + xv.w * w3.x;
            acc[p].y += xv.x * w0.y + xv.y * w1.y + xv.z * w2.y + xv.w * w3.y;
            acc[p].z += xv.x * w0.z + xv.y * w1.z + xv.z * w2.z + xv.w * w3.z;
            acc[p].w += xv.x * w0.w + xv.y * w1.w + xv.z * w2.w + xv.w * w3.w;
        }
    }
    if (which == 0) {
#pragma unroll
        for (int p = 0; p < 4; ++p) {
            int row = tile0 + rg * 4 + p;
            if (row < n) {
                ushort4_t o;
                o[0] = f2bf(acc[p].x); o[1] = f2bf(acc[p].y);
                o[2] = f2bf(acc[p].z); o[3] = f2bf(acc[p].w);
                ((ushort4_t*)outT)[(size_t)row * 32 + c4] = o;
            }
        }
    } else {
        float4 bv = ((const float4*)bdown)[c4];
#pragma unroll
        for (int p = 0; p < 4; ++p) {
            int row = tile0 + rg * 4 + p;
            if (row < n) {
                float4 o;
                o.x = acc[p].x + bv.x; o.y = acc[p].y + bv.y;
                o.z = acc[p].z + bv.z; o.w = acc[p].w + bv.w;
                ((float4*)outB)[(size_t)row * 32 + c4] = o;
            }
        }
    }
}

// ---- cooperative colsum + scan + base (40 blocks, 1 grid barrier), u16 hist ----
__global__ __launch_bounds__(256) void k_mid(const unsigned short* __restrict__ h,
                                             int* bar,
                                             int* __restrict__ rangesum,
                                             int* __restrict__ offsets,
                                             float* __restrict__ dis,
                                             int* __restrict__ bmat) {
    __shared__ int sc[256];
    __shared__ int rsl[NBLK];
    __shared__ int sP;
    int b = blockIdx.x, t = threadIdx.x;
    int i = b * NPB2 + t;
    bool act = (t < NPB2);

    int s = 0;
    if (act) {
#pragma unroll 10
        for (int bb = 0; bb < NB; ++bb) s += h[bb * HP + i];
        dis[i] = rsqrtf((float)(s + 1));   // +1 self-loop
    }
    sc[t] = s;
    __syncthreads();
#pragma unroll
    for (int off = 1; off < 256; off <<= 1) {
        int v = (t >= off) ? sc[t - off] : 0;
        __syncthreads();
        sc[t] += v;
        __syncthreads();
    }
    int lofs = sc[t] - s;
    if (t == 255) rangesum[b] = sc[255];
    gbar(bar, 0, NBLK);

    if (t < NBLK) rsl[t] = rangesum[t];
    __syncthreads();
    if (t == 0) {
        int P = 0;
        for (int bb = 0; bb < b; ++bb) P += rsl[bb];
        sP = P;
        if (b == NBLK - 1) offsets[N_NODES] = P + rsl[b];
    }
    __syncthreads();
    if (act) {
        int run = sP + lofs;
        offsets[i] = run;
#pragma unroll 10
        for (int bb = 0; bb < NB; ++bb) {
            bmat[bb * HP + i] = run;
            run += h[bb * HP + i];
        }
    }
}

// ---- edge-parallel scatter: one edge per thread, packed rec {src, dis[src]} ----
__global__ __launch_bounds__(256) void k_scatter_ep(const int* __restrict__ src,
                                                    const int* __restrict__ dst,
                                                    const unsigned short* __restrict__ rank,
                                                    const int* __restrict__ bmat,
                                                    const float* __restrict__ dis,
                                                    int2* __restrict__ rec) {
    int e = blockIdx.x * 256 + threadIdx.x;          // grid covers E exactly
    int b = blockIdx.x / (CH / 256);                  // 25 blocks per chunk
    int d = dst[e];
    int s = src[e];
    int r = rank[e];
    int pos = bmat[b * HP + d] + r;
    rec[pos] = make_int2(s, __float_as_int(dis[s]));  // dis is 40KB, L2-resident
}

// ---- single GEMM (T2 = h1 @ W2, bf16 out) ----
__global__ __launch_bounds__(256) void k_gemm(const float* __restrict__ X,
                                              const float* __restrict__ W,
                                              unsigned short* __restrict__ Y, int n) {
    __shared__ float xs[32 * 128];
    __shared__ float ws[128 * 128];
    int t = threadIdx.x;
    int tile0 = blockIdx.x * 32;

    const float4* Wv = (const float4*)W;
    float4* wsv = (float4*)ws;
#pragma unroll
    for (int q = 0; q < 16; ++q) wsv[t + 256 * q] = Wv[t + 256 * q];

    const float4* Xv = (const float4*)X;
    float4* xsv = (float4*)xs;
#pragma unroll
    for (int q = 0; q < 4; ++q) {
        int idx = t + 256 * q;
        int row = tile0 + (idx >> 5);
        float4 v = make_float4(0.f, 0.f, 0.f, 0.f);
        if (row < n) v = Xv[(size_t)row * 32 + (idx & 31)];
        xsv[idx] = v;
    }
    __syncthreads();

    int c4 = t & 31;
    int rg = t >> 5;
    float4 acc[4];
#pragma unroll
    for (int p = 0; p < 4; ++p) acc[p] = make_float4(0.f, 0.f, 0.f, 0.f);

    const float4* wsr = (const float4*)ws;
    const float4* xsr = (const float4*)xs;
#pragma unroll 4
    for (int kq = 0; kq < 32; ++kq) {
        float4 w0 = wsr[(4 * kq + 0) * 32 + c4];
        float4 w1 = wsr[(4 * kq + 1) * 32 + c4];
        float4 w2 = wsr[(4 * kq + 2) * 32 + c4];
        float4 w3 = wsr[(4 * kq + 3) * 32 + c4];
#pragma unroll
        for (int p = 0; p < 4; ++p) {
            float4 xv = xsr[(rg * 4 + p) * 32 + kq];
            acc[p].x += xv.x * w0.x + xv.y * w1.x + xv.z * w2.x + xv.w * w3.x;
            acc[p].y += xv.x * w0.y + xv.y * w1.y + xv.z * w2.y + xv.w * w3.y;
            acc[p].z += xv.x * w0.z + xv.y * w1.z + xv.z * w2.z + xv.w * w3.z;
            acc[p].w += xv.x * w0.w + xv.y * w1.w + xv.z * w2.w + xv.w * w3.w;
        }
    }
#pragma unroll
    for (int p = 0; p < 4; ++p) {
        int row = tile0 + rg * 4 + p;
        if (row < n) {
            ushort4_t o;
            o[0] = f2bf(acc[p].x); o[1] = f2bf(acc[p].y);
            o[2] = f2bf(acc[p].z); o[3] = f2bf(acc[p].w);
            ((ushort4_t*)Y)[(size_t)row * 32 + c4] = o;
        }
    }
}

// ---- block-per-node agg edge loop (16 col-lanes x 16 edge-subsets, packed rec) ----
#define AGG_EDGE_LOOP_B                                                        \
    float acc[8];                                                              \
    _Pragma("unroll") for (int j = 0; j < 8; ++j) acc[j] = 0.f;                \
    int e = e0 + es;                                                           \
    for (; e + 48 < e1; e += 64) {                                             \
        int2 r0 = rec[e], r1 = rec[e + 16], r2 = rec[e + 32], r3 = rec[e + 48];\
        float w0 = __int_as_float(r0.y), w1 = __int_as_float(r1.y);            \
        float w2 = __int_as_float(r2.y), w3 = __int_as_float(r3.y);            \
        ushort8_t v0 = T8[(size_t)r0.x * 16 + c8];                             \
        ushort8_t v1 = T8[(size_t)r1.x * 16 + c8];                             \
        ushort8_t v2 = T8[(size_t)r2.x * 16 + c8];                             \
        ushort8_t v3 = T8[(size_t)r3.x * 16 + c8];                             \
        _Pragma("unroll") for (int j = 0; j < 8; ++j)                          \
            acc[j] += w0 * bf2f(v0[j]) + w1 * bf2f(v1[j]) +                    \
                      w2 * bf2f(v2[j]) + w3 * bf2f(v3[j]);                     \
    }                                                                          \
    for (; e + 16 < e1; e += 32) {                                             \
        int2 r0 = rec[e], r1 = rec[e + 16];                                    \
        float w0 = __int_as_float(r0.y), w1 = __int_as_float(r1.y);            \
        ushort8_t v0 = T8[(size_t)r0.x * 16 + c8];                             \
        ushort8_t v1 = T8[(size_t)r1.x * 16 + c8];                             \
        _Pragma("unroll") for (int j = 0; j < 8; ++j)                          \
            acc[j] += w0 * bf2f(v0[j]) + w1 * bf2f(v1[j]);                     \
    }                                                                          \
    if (e < e1) {                                                              \
        int2 r0 = rec[e];                                                      \
        float w0 = __int_as_float(r0.y);                                       \
        ushort8_t v0 = T8[(size_t)r0.x * 16 + c8];                             \
        _Pragma("unroll") for (int j = 0; j < 8; ++j)                          \
            acc[j] += w0 * bf2f(v0[j]);                                        \
    }                                                                          \
    _Pragma("unroll") for (int j = 0; j < 8; ++j) {                            \
        acc[j] += __shfl_xor(acc[j], 16, 64);                                  \
        acc[j] += __shfl_xor(acc[j], 32, 64);                                  \
    }

// ---- layer-1 aggregation: h1 = relu(agg(T1)+b1), block-per-node ----
__global__ __launch_bounds__(256) void k_agg1(const ushort8_t* __restrict__ T8,
                                              const float* __restrict__ dis,
                                              const int* __restrict__ offsets,
                                              const int2* __restrict__ rec,
                                              const float* __restrict__ bias,
                                              float* __restrict__ Y) {
    __shared__ float red[3][16][9];
    int i = blockIdx.x;
    int t = threadIdx.x;
    int c8 = t & 15;
    int es = t >> 4;
    int wave = t >> 6;
    int lane = t & 63;
    int e0 = offsets[i], e1 = offsets[i + 1];

    AGG_EDGE_LOOP_B

    if (wave > 0 && lane < 16) {
#pragma unroll
        for (int j = 0; j < 8; ++j) red[wave - 1][lane][j] = acc[j];
    }
    __syncthreads();
    if (wave == 0 && lane < 16) {
#pragma unroll
        for (int j = 0; j < 8; ++j)
            acc[j] += red[0][lane][j] + red[1][lane][j] + red[2][lane][j];

        float di = dis[i];
        ushort8_t sv = T8[(size_t)i * 16 + c8];
#pragma unroll
        for (int j = 0; j < 8; ++j) acc[j] += di * bf2f(sv[j]);
#pragma unroll
        for (int j = 0; j < 8; ++j)
            acc[j] = fmaxf(di * acc[j] + bias[c8 * 8 + j], 0.f);

        float4* Y4 = (float4*)Y;
        Y4[(size_t)i * 32 + c8 * 2]     = make_float4(acc[0], acc[1], acc[2], acc[3]);
        Y4[(size_t)i * 32 + c8 * 2 + 1] = make_float4(acc[4], acc[5], acc[6], acc[7]);
    }
}

// ---- layer-2 aggregation + residual + all three heads, block-per-node ----
__global__ __launch_bounds__(256) void k_agg2h(const ushort8_t* __restrict__ T8,
                                               const float* __restrict__ dis,
                                               const int* __restrict__ offsets,
                                               const int2* __restrict__ rec,
                                               const float* __restrict__ bias,
                                               const float* __restrict__ resid,
                                               const float* __restrict__ Wlin,
                                               const float* __restrict__ blin,
                                               const float* __restrict__ Wd2,
                                               const float* __restrict__ bd2,
                                               const float* __restrict__ Wd3,
                                               const float* __restrict__ bd3,
                                               float* __restrict__ out1,
                                               float* __restrict__ out2,
                                               float* __restrict__ out3) {
    __shared__ float red[3][16][9];
    __shared__ float hrow[128];
    int i = blockIdx.x;
    int t = threadIdx.x;
    int c8 = t & 15;
    int es = t >> 4;
    int wave = t >> 6;
    int lane = t & 63;
    int e0 = offsets[i], e1 = offsets[i + 1];

    AGG_EDGE_LOOP_B

    if (wave > 0 && lane < 16) {
#pragma unroll
        for (int j = 0; j < 8; ++j) red[wave - 1][lane][j] = acc[j];
    }
    __syncthreads();
    if (wave == 0 && lane < 16) {
#pragma unroll
        for (int j = 0; j < 8; ++j)
            acc[j] += red[0][lane][j] + red[1][lane][j] + red[2][lane][j];

        float di = dis[i];
        ushort8_t sv = T8[(size_t)i * 16 + c8];
#pragma unroll
        for (int j = 0; j < 8; ++j) acc[j] += di * bf2f(sv[j]);

        const float4* rv4 = (const float4*)resid;
        float4 r0 = rv4[(size_t)i * 32 + c8 * 2];
        float4 r1 = rv4[(size_t)i * 32 + c8 * 2 + 1];
#pragma unroll
        for (int j = 0; j < 8; ++j) acc[j] = di * acc[j] + bias[c8 * 8 + j];
        acc[0] += r0.x; acc[1] += r0.y; acc[2] += r0.z; acc[3] += r0.w;
        acc[4] += r1.x; acc[5] += r1.y; acc[6] += r1.z; acc[7] += r1.w;

#pragma unroll
        for (int j = 0; j < 8; ++j) hrow[c8 * 8 + j] = acc[j];
    }
    __syncthreads();

    if (wave == 0) {
        float h0 = hrow[lane];
        float h1 = hrow[64 + lane];
        float p2 = h0 * Wd2[lane] + h1 * Wd2[64 + lane];
        float p3 = h0 * Wd3[lane] + h1 * Wd3[64 + lane];
#pragma unroll
        for (int d = 1; d < 64; d <<= 1) {
            p2 += __shfl_xor(p2, d, 64);
            p3 += __shfl_xor(p3, d, 64);
        }
        if (lane == 0) {
            out2[i] = p2 + bd2[0];
            out3[i] = p3 + bd3[0];
        }
        int c = lane & 15, kg = lane >> 4;
        float z = 0.f;
#pragma unroll 8
        for (int j = 0; j < 32; ++j) {
            int k = kg * 32 + j;
            z += hrow[k] * Wlin[k * 16 + c];
        }
        z += __shfl_xor(z, 16, 64);
        z += __shfl_xor(z, 32, 64);
        z += blin[c];
        float m = z;
#pragma unroll
        for (int d = 1; d < 16; d <<= 1) m = fmaxf(m, __shfl_xor(m, d, 64));
        float ex = expf(z - m);
        float ssum = ex;
#pragma unroll
        for (int d = 1; d < 16; d <<= 1) ssum += __shfl_xor(ssum, d, 64);
        float lsm = z - m - logf(ssum);
        if (lane < 16) out1[(size_t)i * 16 + c] = lsm;
    }
}

extern "C" void kernel_launch(void* const* d_in, const int* in_sizes, int n_in,
                              void* d_out, int out_size, void* d_ws, size_t ws_size,
                              hipStream_t stream) {
    const float* x     = (const float*)d_in[0];
    const int*   ei    = (const int*)d_in[1];
    const float* W1    = (const float*)d_in[2];
    const float* b1    = (const float*)d_in[3];
    const float* W2    = (const float*)d_in[4];
    const float* b2    = (const float*)d_in[5];
    const float* Wlin1 = (const float*)d_in[6];
    const float* blin1 = (const float*)d_in[7];
    const float* Wdeg2 = (const float*)d_in[8];
    const float* bdeg2 = (const float*)d_in[9];
    const float* Wdeg3 = (const float*)d_in[10];
    const float* bdeg3 = (const float*)d_in[11];
    const float* Wdown = (const float*)d_in[12];
    const float* bdown = (const float*)d_in[13];

    const int n = N_NODES, E = N_EDGES;
    const int* src = ei;
    const int* dst = ei + E;

    char* ws = (char*)d_ws;
    int*            bar      = (int*)ws;                          // 64 ints
    unsigned short* hmat     = (unsigned short*)(bar + 64);       // NB*HP u16
    int*            bmat     = (int*)(hmat + NB * HP);            // NB*HP i32
    int*            rangesum = bmat + NB * HP;                    // 64
    int*            offsets  = rangesum + 64;                     // 10048
    float*          dis      = (float*)(offsets + 10048);         // 10016
    unsigned short* rank     = (unsigned short*)(dis + HP);       // E u16
    int2*           rec      = (int2*)(rank + E);                 // E x 8B
    unsigned short* bufT     = (unsigned short*)(rec + E);        // bf16 n*128
    float*          bufB     = (float*)(bufT + (size_t)n * 128);  // f32 n*128
    float*          bufC     = bufB + (size_t)n * 128;            // f32 n*128

    // 1: histogram+rank (100 blocks) || dual GEMM (626 blocks)
    k_hist_gemm2<<<NB + 2 * GB, 256, 0, stream>>>(dst, hmat, rank, bar, x, W1,
                                                  Wdown, bdown, bufT, bufB, n);
    // 2: colsum/scan/base (cooperative, 40 blocks)
    k_mid<<<NBLK, 256, 0, stream>>>(hmat, bar, rangesum, offsets, dis, bmat);
    // 3: edge-parallel scatter (2500 blocks, 1 edge/thread, packed rec)
    k_scatter_ep<<<E / 256, 256, 0, stream>>>(src, dst, rank, bmat, dis, rec);
    // 4: h1 = relu(agg(T1) + b1), block-per-node (max wave count)
    k_agg1<<<n, 256, 0, stream>>>((const ushort8_t*)bufT, dis, offsets, rec,
                                  b1, bufC);
    // 5: T2 = h1 @ W2
    k_gemm<<<(n + 31) / 32, 256, 0, stream>>>(bufC, W2, bufT, n);
    // 6: h2 = agg(T2) + b2 + orig, fused heads, block-per-node
    float* out1 = (float*)d_out;
    float* out2 = out1 + (size_t)n * 16;
    float* out3 = out2 + n;
    k_agg2h<<<n, 256, 0, stream>>>((const ushort8_t*)bufT, dis, offsets, rec,
                                   b2, bufB, Wlin1, blin1, Wdeg2, bdeg2,
                                   Wdeg3, bdeg3, out1, out2, out3);
}